// Round 5
// baseline (589.639 us; speedup 1.0000x reference)
//
#include <hip/hip_runtime.h>

#define BEV_H 512
#define BEV_W 512
#define BEV_HW (BEV_H * BEV_W)
#define NB 8
#define NP 30000
#define NC 64

typedef float floatx4 __attribute__((ext_vector_type(4)));

// Phase 2: record, per BEV cell, the highest pillar index p that maps to it.
// Matches numpy/JAX-CPU scatter "last write wins" semantics (highest p wins).
__global__ void scatter_winner_kernel(const int* __restrict__ coords,
                                      int* __restrict__ winner) {
    int idx = blockIdx.x * blockDim.x + threadIdx.x;   // over NB*NP
    if (idx >= NB * NP) return;
    int b = idx / NP;
    int p = idx - b * NP;
    int2 c2 = ((const int2*)coords)[idx];              // coords[b][p][{x,y}]
    int gx = c2.x;
    int gy = c2.y;
    if (gx >= 0 && gx < BEV_W && gy >= 0 && gy < BEV_H) {
        atomicMax(&winner[b * BEV_HW + gy * BEV_W + gx], p);
    }
}

// Phase 3, round-5: round-4 thread body (4 cells x 4 channels, one round
// trip: int4 winner load -> 4 indep float4 gathers -> 4x4 transpose -> 4
// nontemporal coalesced stores) + REUSE-BY-CONSTRUCTION grid swizzle.
//
// Linear block id layout:  id = b*4096 + cb_high*128 + g*8 + cb_low
//   - the 16 g-replicas of one cell-block are delta=8 apart: SAME XCD
//     (id%8 = cb_low unchanged) and within a 128-id span -> co-resident.
//     Winner chunk (4 KB): 1 fetch + 15 L2 hits (was: re-fetched, delta=256
//     straddled the per-XCD residency window).
//   - the 4 g-quads sharing each 64-B feat line are delta<=24 apart ->
//     line fetched once, 3 L2 hits.
//   - cb_low spreads cell-blocks across all 8 XCDs -> disjoint winner/feat
//     working sets per XCD L2.
// Stores stay nontemporal so the 537-MB out stream cannot evict this reuse.
__global__ void __launch_bounds__(256)
gather_out_kernel(const float* __restrict__ feat,
                  const int* __restrict__ winner,
                  float* __restrict__ out) {
    const int id      = blockIdx.x;
    const int cb_low  = id & 7;
    const int g       = (id >> 3) & 15;          // channel quad: 4g..4g+3
    const int cb_high = (id >> 7) & 31;
    const int b       = id >> 12;                // batch
    const int cellblk = cb_high * 8 + cb_low;    // 256 cell-blocks / batch
    const int cell    = (cellblk * 256 + threadIdx.x) << 2;   // 4 cells

    const int4 w4 = *(const int4*)(winner + (size_t)b * BEV_HW + cell);
    const int w[4] = {w4.x, w4.y, w4.z, w4.w};

    const float* __restrict__ fb = feat + (size_t)b * NP * NC + g * 4;

    // 4 independent 16-B gathers: v[k] = cell k, channels 4g..4g+3
    float4 v[4];
    #pragma unroll
    for (int k = 0; k < 4; ++k) {
        const float* __restrict__ rk = fb + (size_t)(w[k] < 0 ? 0 : w[k]) * NC;
        v[k] = *(const float4*)rk;
    }
    #pragma unroll
    for (int k = 0; k < 4; ++k) {
        if (w[k] < 0) v[k] = make_float4(0.f, 0.f, 0.f, 0.f);
    }

    // Transpose -> one coalesced float4 store per channel plane (4 planes)
    float* __restrict__ ob =
        out + ((size_t)b * NC + g * 4) * BEV_HW + cell;
    floatx4 s0 = {v[0].x, v[1].x, v[2].x, v[3].x};
    floatx4 s1 = {v[0].y, v[1].y, v[2].y, v[3].y};
    floatx4 s2 = {v[0].z, v[1].z, v[2].z, v[3].z};
    floatx4 s3 = {v[0].w, v[1].w, v[2].w, v[3].w};
    __builtin_nontemporal_store(s0, (floatx4*)(ob + (size_t)0 * BEV_HW));
    __builtin_nontemporal_store(s1, (floatx4*)(ob + (size_t)1 * BEV_HW));
    __builtin_nontemporal_store(s2, (floatx4*)(ob + (size_t)2 * BEV_HW));
    __builtin_nontemporal_store(s3, (floatx4*)(ob + (size_t)3 * BEV_HW));
}

extern "C" void kernel_launch(void* const* d_in, const int* in_sizes, int n_in,
                              void* d_out, int out_size, void* d_ws, size_t ws_size,
                              hipStream_t stream) {
    const float* feat   = (const float*)d_in[0];   // (8, 30000, 64) f32
    const int*   coords = (const int*)d_in[1];     // (8, 30000, 2) i32
    float*       out    = (float*)d_out;           // (8, 64, 512, 512) f32
    int*         winner = (int*)d_ws;              // NB*BEV_HW ints = 8 MB

    // Phase 1: winner = -1 everywhere (0xFF bytes). Capturable memset node.
    hipMemsetAsync(winner, 0xFF, (size_t)NB * BEV_HW * sizeof(int), stream);

    // Phase 2: atomicMax scatter of pillar indices.
    {
        int total = NB * NP;
        int block = 256;
        int grid  = (total + block - 1) / block;
        scatter_winner_kernel<<<grid, block, 0, stream>>>(coords, winner);
    }

    // Phase 3: gather + coalesced write of the full (8,64,512,512) output.
    // 4 cells x 4 channels per thread, 1-D swizzled grid (g at delta=8).
    {
        dim3 block(256, 1, 1);
        dim3 grid(NB * 16 * (BEV_HW / (4 * 256)), 1, 1);   // 32768 blocks
        gather_out_kernel<<<grid, block, 0, stream>>>(feat, winner, out);
    }
}

// Round 6
// 575.491 us; speedup vs baseline: 1.0246x; 1.0246x over previous
//
#include <hip/hip_runtime.h>

#define BEV_H 512
#define BEV_W 512
#define BEV_HW (BEV_H * BEV_W)
#define NB 8
#define NP 30000
#define NC 64

typedef float floatx4 __attribute__((ext_vector_type(4)));

// Phase 2: record, per BEV cell, the highest pillar index p that maps to it.
// Matches numpy/JAX-CPU scatter "last write wins" semantics (highest p wins).
__global__ void scatter_winner_kernel(const int* __restrict__ coords,
                                      int* __restrict__ winner) {
    int idx = blockIdx.x * blockDim.x + threadIdx.x;   // over NB*NP
    if (idx >= NB * NP) return;
    int b = idx / NP;
    int p = idx - b * NP;
    int2 c2 = ((const int2*)coords)[idx];              // coords[b][p][{x,y}]
    int gx = c2.x;
    int gy = c2.y;
    if (gx >= 0 && gx < BEV_W && gy >= 0 && gy < BEV_H) {
        atomicMax(&winner[b * BEV_HW + gy * BEV_W + gx], p);
    }
}

// Phase 3, round-6: round-4 thread body and grid ORDER (y = b*16+g,
// x-fastest => store stream marches linearly through each plane-quad,
// the property round-5's swizzle broke), with block size 1024.
//   - grid.x shrinks 256 -> 64, so the 16 g-replicas of a winner chunk
//     and the 4 g-quads sharing each 64-B feat line sit delta=64/128/192
//     apart: same XCD (delta % 8 == 0) AND co-resident (~512 blocks in
//     flight) -> winner + feat re-reads L2-hit by construction, while
//     the write order stays bit-identical to round 4.
//   - each block stores 16 KB contiguous per plane (was 4 KB): better
//     DRAM page locality on the dominant 537-MB write stream.
//   - thread body unchanged: int4 winner load, 4 indep float4 gathers,
//     4x4 transpose, 4 nontemporal coalesced float4 stores.
__global__ void __launch_bounds__(1024)
gather_out_kernel(const float* __restrict__ feat,
                  const int* __restrict__ winner,
                  float* __restrict__ out) {
    const int b    = blockIdx.y >> 4;                 // batch
    const int g    = blockIdx.y & 15;                 // channel quad: 4g..4g+3
    const int cell = (blockIdx.x * blockDim.x + threadIdx.x) << 2;  // 4 cells

    const int4 w4 = *(const int4*)(winner + (size_t)b * BEV_HW + cell);
    const int w[4] = {w4.x, w4.y, w4.z, w4.w};

    const float* __restrict__ fb = feat + (size_t)b * NP * NC + g * 4;

    // 4 independent 16-B gathers: v[k] = cell k, channels 4g..4g+3
    float4 v[4];
    #pragma unroll
    for (int k = 0; k < 4; ++k) {
        const float* __restrict__ rk = fb + (size_t)(w[k] < 0 ? 0 : w[k]) * NC;
        v[k] = *(const float4*)rk;
    }
    #pragma unroll
    for (int k = 0; k < 4; ++k) {
        if (w[k] < 0) v[k] = make_float4(0.f, 0.f, 0.f, 0.f);
    }

    // Transpose -> one coalesced float4 store per channel plane (4 planes)
    float* __restrict__ ob =
        out + ((size_t)b * NC + g * 4) * BEV_HW + cell;
    floatx4 s0 = {v[0].x, v[1].x, v[2].x, v[3].x};
    floatx4 s1 = {v[0].y, v[1].y, v[2].y, v[3].y};
    floatx4 s2 = {v[0].z, v[1].z, v[2].z, v[3].z};
    floatx4 s3 = {v[0].w, v[1].w, v[2].w, v[3].w};
    __builtin_nontemporal_store(s0, (floatx4*)(ob + (size_t)0 * BEV_HW));
    __builtin_nontemporal_store(s1, (floatx4*)(ob + (size_t)1 * BEV_HW));
    __builtin_nontemporal_store(s2, (floatx4*)(ob + (size_t)2 * BEV_HW));
    __builtin_nontemporal_store(s3, (floatx4*)(ob + (size_t)3 * BEV_HW));
}

extern "C" void kernel_launch(void* const* d_in, const int* in_sizes, int n_in,
                              void* d_out, int out_size, void* d_ws, size_t ws_size,
                              hipStream_t stream) {
    const float* feat   = (const float*)d_in[0];   // (8, 30000, 64) f32
    const int*   coords = (const int*)d_in[1];     // (8, 30000, 2) i32
    float*       out    = (float*)d_out;           // (8, 64, 512, 512) f32
    int*         winner = (int*)d_ws;              // NB*BEV_HW ints = 8 MB

    // Phase 1: winner = -1 everywhere (0xFF bytes). Capturable memset node.
    hipMemsetAsync(winner, 0xFF, (size_t)NB * BEV_HW * sizeof(int), stream);

    // Phase 2: atomicMax scatter of pillar indices.
    {
        int total = NB * NP;
        int block = 256;
        int grid  = (total + block - 1) / block;
        scatter_winner_kernel<<<grid, block, 0, stream>>>(coords, winner);
    }

    // Phase 3: gather + coalesced write of the full (8,64,512,512) output.
    // 4 cells x 4 channels per thread, block=1024, round-4 grid order.
    {
        dim3 block(1024, 1, 1);
        dim3 grid(BEV_HW / (4 * 1024), NB * 16, 1);  // 64 x 128 = 8192 blocks
        gather_out_kernel<<<grid, block, 0, stream>>>(feat, winner, out);
    }
}